// Round 4
// baseline (590.726 us; speedup 1.0000x reference)
//
#include <hip/hip_runtime.h>

// Problem constants (from reference): B=8192 rows, ITEM_NUM=10000 cols.
#define ROWS 8192
#define COLS 10000
#define COLS4 (COLS / 4)     // 2500 float4 per row; 40000 B row stride (16B-aligned)
#define BLK 256
#define ROWS_PER_BLK 8
#define NBLOCKS (ROWS / ROWS_PER_BLK)   // 1024 = 4 blocks/CU, fully resident
#define TAIL (COLS4 - 2304)             // 196: float4 idx 2304..2499, threads 0..195

// Native clang vector type (HIP float4 is a class; this maps to 4 VGPRs;
// accepted by __builtin_nontemporal_load).
typedef float vf4 __attribute__((ext_vector_type(4)));

__device__ __forceinline__ float dot4(vf4 a, vf4 b) {
    return a.x * b.x + a.y * b.y + a.z * b.z + a.w * b.w;
}

// One block per 8 consecutive rows. W is preloaded into REGISTERS (10 vf4 =
// 40 VGPR per thread, thread t owns W4[t], W4[t+256], ..) and reused for 8
// rows, so the hot loop's in-order vmcnt queue holds ONLY homogeneous-latency
// HBM stream loads (h/t) — no short-latency L2 W-loads interleaved, 33% fewer
// VMEM instructions. launch_bounds(256,4) caps VGPR at 128 so all 1024 blocks
// co-reside (4/CU). No per-row barrier: per-wave partials park in 256 B LDS,
// one barrier at block end -> loads pipeline across row boundaries.
__global__ __launch_bounds__(BLK, 4) void qloss_rows_kernel(
    const float* __restrict__ hidden,
    const float* __restrict__ target,
    const float* __restrict__ rewards,
    const float* __restrict__ discount,   // 1-element
    const unsigned char* __restrict__ is_done,
    const float* __restrict__ W,          // [10000]
    const float* __restrict__ bias,       // 1-element
    float* __restrict__ partial)          // [ROWS]
{
    const int tid  = threadIdx.x;
    const int lane = tid & 63;
    const int wid  = tid >> 6;

    // ---- W preload: 10 float4 per thread (slot s covers idx tid + 256*s) ----
    const vf4* __restrict__ w4 = (const vf4*)W;
    vf4 wr0 = w4[tid];
    vf4 wr1 = w4[tid + 256];
    vf4 wr2 = w4[tid + 512];
    vf4 wr3 = w4[tid + 768];
    vf4 wr4 = w4[tid + 1024];
    vf4 wr5 = w4[tid + 1280];
    vf4 wr6 = w4[tid + 1536];
    vf4 wr7 = w4[tid + 1792];
    vf4 wr8 = w4[tid + 2048];
    vf4 wr9 = {0.f, 0.f, 0.f, 0.f};
    if (tid < TAIL) wr9 = w4[tid + 2304];

    __shared__ float smh[4][ROWS_PER_BLK];
    __shared__ float smt[4][ROWS_PER_BLK];

    const int row0 = blockIdx.x * ROWS_PER_BLK;

    for (int r = 0; r < ROWS_PER_BLK; ++r) {
        const int row = row0 + r;
        const vf4* __restrict__ h4 = (const vf4*)(hidden + (size_t)row * COLS);
        const vf4* __restrict__ t4 = (const vf4*)(target + (size_t)row * COLS);

        float ah0 = 0.f, ah1 = 0.f, at0 = 0.f, at1 = 0.f;
        // 9 full block-stride rounds (idx 0..2303), W from registers.
        {
            vf4 h0 = __builtin_nontemporal_load(&h4[tid]);
            vf4 h1 = __builtin_nontemporal_load(&h4[tid + 256]);
            vf4 t0 = __builtin_nontemporal_load(&t4[tid]);
            vf4 t1 = __builtin_nontemporal_load(&t4[tid + 256]);
            ah0 += dot4(h0, wr0); ah1 += dot4(h1, wr1);
            at0 += dot4(t0, wr0); at1 += dot4(t1, wr1);
        }
        {
            vf4 h0 = __builtin_nontemporal_load(&h4[tid + 512]);
            vf4 h1 = __builtin_nontemporal_load(&h4[tid + 768]);
            vf4 t0 = __builtin_nontemporal_load(&t4[tid + 512]);
            vf4 t1 = __builtin_nontemporal_load(&t4[tid + 768]);
            ah0 += dot4(h0, wr2); ah1 += dot4(h1, wr3);
            at0 += dot4(t0, wr2); at1 += dot4(t1, wr3);
        }
        {
            vf4 h0 = __builtin_nontemporal_load(&h4[tid + 1024]);
            vf4 h1 = __builtin_nontemporal_load(&h4[tid + 1280]);
            vf4 t0 = __builtin_nontemporal_load(&t4[tid + 1024]);
            vf4 t1 = __builtin_nontemporal_load(&t4[tid + 1280]);
            ah0 += dot4(h0, wr4); ah1 += dot4(h1, wr5);
            at0 += dot4(t0, wr4); at1 += dot4(t1, wr5);
        }
        {
            vf4 h0 = __builtin_nontemporal_load(&h4[tid + 1536]);
            vf4 h1 = __builtin_nontemporal_load(&h4[tid + 1792]);
            vf4 t0 = __builtin_nontemporal_load(&t4[tid + 1536]);
            vf4 t1 = __builtin_nontemporal_load(&t4[tid + 1792]);
            ah0 += dot4(h0, wr6); ah1 += dot4(h1, wr7);
            at0 += dot4(t0, wr6); at1 += dot4(t1, wr7);
        }
        {
            vf4 h0 = __builtin_nontemporal_load(&h4[tid + 2048]);
            vf4 t0 = __builtin_nontemporal_load(&t4[tid + 2048]);
            ah0 += dot4(h0, wr8);
            at0 += dot4(t0, wr8);
        }
        // Tail: idx 2304..2499, threads 0..195 (guarded: last row must not
        // read past the buffer end).
        if (tid < TAIL) {
            vf4 h1 = __builtin_nontemporal_load(&h4[tid + 2304]);
            vf4 t1 = __builtin_nontemporal_load(&t4[tid + 2304]);
            ah1 += dot4(h1, wr9);
            at1 += dot4(t1, wr9);
        }

        float ah = ah0 + ah1;
        float at = at0 + at1;
        #pragma unroll
        for (int off = 32; off > 0; off >>= 1) {
            ah += __shfl_down(ah, off, 64);
            at += __shfl_down(at, off, 64);
        }
        if (lane == 0) { smh[wid][r] = ah; smt[wid][r] = at; }
        // no barrier: each wave writes only its own slots; next row's loads
        // can issue immediately.
    }

    __syncthreads();

    // 8 threads finish 8 rows.
    if (tid < ROWS_PER_BLK) {
        const int row = row0 + tid;
        float AH = smh[0][tid] + smh[1][tid] + smh[2][tid] + smh[3][tid];
        float AT = smt[0][tid] + smt[1][tid] + smt[2][tid] + smt[3][tid];
        float b  = bias[0];
        float q  = fmaxf(AH + b, 0.f);
        float nq = fmaxf(AT + b, 0.f);
        float loss = fabsf(rewards[row] + discount[0] * nq - q);
        partial[row] = is_done[row] ? 0.f : loss;
    }
}

// Single-block final reduction: sum 8192 partials, divide by B, write d_out[0].
// Must WRITE (not accumulate) since d_out is poisoned 0xAA before timed runs.
__global__ __launch_bounds__(BLK) void qloss_reduce_kernel(
    const float* __restrict__ partial,
    float* __restrict__ out)
{
    float s = 0.f;
    for (int i = threadIdx.x; i < ROWS; i += BLK) s += partial[i];

    #pragma unroll
    for (int off = 32; off > 0; off >>= 1) s += __shfl_down(s, off, 64);

    __shared__ float sm[BLK / 64];
    const int lane = threadIdx.x & 63;
    const int wid  = threadIdx.x >> 6;
    if (lane == 0) sm[wid] = s;
    __syncthreads();

    if (threadIdx.x == 0) {
        float total = sm[0] + sm[1] + sm[2] + sm[3];
        out[0] = total / (float)ROWS;
    }
}

extern "C" void kernel_launch(void* const* d_in, const int* in_sizes, int n_in,
                              void* d_out, int out_size, void* d_ws, size_t ws_size,
                              hipStream_t stream) {
    // setup_inputs() order:
    // 0: hidden_states [8192,10000] f32
    // 1: actions       [8192]       int32  (unused by reference)
    // 2: rewards       [8192]       f32
    // 3: discount      [1]          f32
    // 4: targetQs_s    [8192,10000] f32
    // 5: is_done       [8192]       bool (all false; read as bytes)
    // 6: W             [1,10000]    f32
    // 7: b             [1]          f32
    const float*         hidden   = (const float*)d_in[0];
    const float*         rewards  = (const float*)d_in[2];
    const float*         discount = (const float*)d_in[3];
    const float*         target   = (const float*)d_in[4];
    const unsigned char* is_done  = (const unsigned char*)d_in[5];
    const float*         W        = (const float*)d_in[6];
    const float*         b        = (const float*)d_in[7];
    float*               out      = (float*)d_out;
    float*               partial  = (float*)d_ws;   // needs ROWS*4 = 32 KB

    qloss_rows_kernel<<<NBLOCKS, BLK, 0, stream>>>(
        hidden, target, rewards, discount, is_done, W, b, partial);
    qloss_reduce_kernel<<<1, BLK, 0, stream>>>(partial, out);
}